// Round 4
// baseline (628.534 us; speedup 1.0000x reference)
//
#include <hip/hip_runtime.h>

#define NB 8
#define NH 56
#define NW 56
#define NHW 3136          // NH*NW
#define NCHW 802816
#define NPIX 25088        // NB*NHW
#define NHP 58            // padded
#define EPSV 1e-5f
#define LSTR 74           // LDS row stride in shorts (37 dwords, odd -> conflict-free)

typedef float f32x4 __attribute__((ext_vector_type(4)));
typedef __bf16 bf16x8 __attribute__((ext_vector_type(8)));

__device__ __forceinline__ unsigned short f2b(float f) {
  unsigned int u = __float_as_uint(f);
  u += 0x7FFFu + ((u >> 16) & 1u);
  return (unsigned short)(u >> 16);
}
__device__ __forceinline__ float blo(unsigned int u){ return __uint_as_float(u << 16); }
__device__ __forceinline__ float bhi(unsigned int u){ return __uint_as_float(u & 0xFFFF0000u); }

// ---------------------------------------------------------------------------
// P1: x NCHW fp32 -> xbp padded-NHWC bf16 [b][y+1][x+1][c] (58x58, border=0
// via preceding memset). grid 392, block 256 (64 px x 4 ch-groups)
// ---------------------------------------------------------------------------
__global__ __launch_bounds__(256) void prep_x(
    const float* __restrict__ x, unsigned short* __restrict__ xbp)
{
  const int t  = threadIdx.x;
  const int px = blockIdx.x*64 + (t & 63);
  const int cg = (t >> 6) * 64;
  const int b  = px / NHW, rem = px % NHW;
  const int ho = rem / NW, wo = rem % NW;
  const float* src = x + (size_t)b*NCHW + rem;
  unsigned short* dst = xbp + ((size_t)(b*NHP + ho + 1)*NHP + wo + 1)*256;
  for (int c = cg; c < cg+64; c += 2) {
    float v0 = src[(size_t)c*NHW];
    float v1 = src[(size_t)(c+1)*NHW];
    unsigned int pk = ((unsigned int)f2b(v1) << 16) | (unsigned int)f2b(v0);
    *(unsigned int*)(dst + c) = pk;
  }
}

// ---------------------------------------------------------------------------
// P2: w [co][ci][3][3] fp32 -> wp [co][k*256+ci] bf16 (K-major per co row)
// ---------------------------------------------------------------------------
__global__ __launch_bounds__(256) void prep_w(
    const float* __restrict__ w, unsigned short* __restrict__ wp)
{
  int i = blockIdx.x*256 + threadIdx.x;    // 589824 exact
  int co = i / 2304;
  int r  = i % 2304;
  int k  = r >> 8;
  int ci = r & 255;
  wp[i] = f2b(w[((size_t)co*256 + ci)*9 + k]);
}

// ---------------------------------------------------------------------------
// GEMM1: conv3x3 + BN + ReLU -> t1b [px][co] bf16
// BM=128 BN=128 BK=64; 256 thr = 2x2 waves, each 64x64 (4x4 16x16 tiles)
// grid (196, 2)
// ---------------------------------------------------------------------------
__global__ __launch_bounds__(256, 2) void gemm_conv1(
    const unsigned short* __restrict__ xbp, const unsigned short* __restrict__ w1p,
    const float* __restrict__ gam, const float* __restrict__ bet,
    const float* __restrict__ mu,  const float* __restrict__ var,
    unsigned short* __restrict__ t1b)
{
  __shared__ unsigned short Al[128*LSTR];
  __shared__ unsigned short Bl[128*LSTR];
  const int m0   = blockIdx.x * 128;
  const int n0   = blockIdx.y * 128;
  const int t    = threadIdx.x;
  const int lane = t & 63;
  const int wv   = t >> 6;
  const int wm   = (wv & 1) * 64;
  const int wn   = (wv >> 1) * 64;
  const int quad = lane >> 4;
  const int l15  = lane & 15;

  // staging identity: A-px for this thread
  const int apx = t & 127;
  const int gb  = t >> 7;           // 0/1
  const int px  = m0 + apx;
  const int b   = px / NHW, rem = px % NHW;
  const int ho  = rem / NW, wo = rem % NW;
  const unsigned int pxbase = ((unsigned int)(b*NHP + ho)*NHP + wo)*256u; // tap(ky,kx)-> +(ky*58+kx)*256

  f32x4 acc[4][4];
  #pragma unroll
  for (int i = 0; i < 4; ++i)
    #pragma unroll
    for (int j = 0; j < 4; ++j) acc[i][j] = (f32x4)(0.f);

  for (int r = 0; r < 36; ++r) {
    const int k = r >> 2, cic = r & 3;
    const int ky = k/3, kx = k - ky*3;
    __syncthreads();
    // stage A: 4 uint4 per thread (px fixed, 8-ci groups g8 = gb+2u)
    {
      const unsigned short* src = xbp + pxbase + (unsigned int)((ky*NHP + kx)*256 + cic*64);
      #pragma unroll
      for (int u = 0; u < 4; ++u) {
        const int g8 = gb + 2*u;
        uint4 q = *(const uint4*)(src + g8*8);
        *(uint4*)(&Al[apx*LSTR + g8*8]) = q;
      }
    }
    // stage B: 4 x 16B per thread
    {
      #pragma unroll
      for (int u = 0; u < 4; ++u) {
        int tau = t + u*256;
        int row = tau >> 3, seg = tau & 7;
        uint4 q = *(const uint4*)(w1p + (size_t)(n0 + row)*2304 + r*64 + seg*8);
        *(uint4*)(&Bl[row*LSTR + seg*8]) = q;
      }
    }
    __syncthreads();
    #pragma unroll
    for (int kk = 0; kk < 2; ++kk) {
      bf16x8 af[4], bfr[4];
      #pragma unroll
      for (int mt = 0; mt < 4; ++mt)
        af[mt] = *(const bf16x8*)(&Al[(wm + mt*16 + l15)*LSTR + kk*32 + quad*8]);
      #pragma unroll
      for (int nt = 0; nt < 4; ++nt)
        bfr[nt] = *(const bf16x8*)(&Bl[(wn + nt*16 + l15)*LSTR + kk*32 + quad*8]);
      #pragma unroll
      for (int mt = 0; mt < 4; ++mt)
        #pragma unroll
        for (int nt = 0; nt < 4; ++nt)
          acc[mt][nt] = __builtin_amdgcn_mfma_f32_16x16x32_bf16(af[mt], bfr[nt], acc[mt][nt], 0, 0, 0);
    }
  }
  // epilogue: BN + ReLU -> bf16 [px][co]
  #pragma unroll
  for (int nt = 0; nt < 4; ++nt) {
    const int co = n0 + wn + nt*16 + l15;
    const float inv  = gam[co] * rsqrtf(var[co] + EPSV);
    const float beta = bet[co] - mu[co]*inv;
    #pragma unroll
    for (int mt = 0; mt < 4; ++mt) {
      const int mb = m0 + wm + mt*16 + quad*4;
      #pragma unroll
      for (int rr = 0; rr < 4; ++rr) {
        float val = acc[mt][nt][rr]*inv + beta;
        val = val > 0.f ? val : 0.f;
        t1b[(size_t)(mb + rr)*256 + co] = f2b(val);
      }
    }
  }
}

// ---------------------------------------------------------------------------
// K2: toff += conv3x3(t1b, off_w) (+off_b on chunk 0); toff pre-zeroed
// ---------------------------------------------------------------------------
__global__ __launch_bounds__(256) void offset_conv(
    const unsigned short* __restrict__ t1b, const float* __restrict__ ow,
    const float* __restrict__ ob, float* __restrict__ toff)
{
  const int p = blockIdx.x*256 + threadIdx.x;
  const int cichunk = blockIdx.y * 32;
  const int b  = p / NHW, rem = p % NHW;
  const int ho = rem / NW, wo = rem % NW;

  float acc[18];
  if (blockIdx.y == 0) {
    #pragma unroll
    for (int c = 0; c < 18; ++c) acc[c] = ob[c];
  } else {
    #pragma unroll
    for (int c = 0; c < 18; ++c) acc[c] = 0.f;
  }

  #pragma unroll
  for (int ky = 0; ky < 3; ++ky) {
    int y = ho - 1 + ky;
    if (y < 0 || y >= NH) continue;
    #pragma unroll
    for (int kx = 0; kx < 3; ++kx) {
      int xx = wo - 1 + kx;
      if (xx < 0 || xx >= NW) continue;
      const int k = ky*3 + kx;
      const unsigned short* base = t1b + ((size_t)(b*NH + y)*NW + xx)*256 + cichunk;
      for (int q = 0; q < 8; ++q) {
        uint2 u = *(const uint2*)(base + q*4);
        float f0 = blo(u.x), f1 = bhi(u.x), f2v = blo(u.y), f3 = bhi(u.y);
        const int ci = cichunk + q*4;
        #pragma unroll
        for (int c = 0; c < 18; ++c) {
          const float* wr = ow + ((size_t)c*256 + ci)*9 + k;   // uniform -> s_load
          acc[c] += f0*wr[0] + f1*wr[9] + f2v*wr[18] + f3*wr[27];
        }
      }
    }
  }
  float* od = toff + (size_t)b*(18*NHW) + rem;
  #pragma unroll
  for (int c = 0; c < 18; ++c)
    atomicAdd(od + c*NHW, acc[c]);
}

// ---------------------------------------------------------------------------
// GEMM2: deform_conv + BN + residual + ReLU -> out NCHW fp32
// same tile shape as GEMM1; A staged via on-the-fly bilinear sampling
// ---------------------------------------------------------------------------
__global__ __launch_bounds__(256, 2) void gemm_deform(
    const unsigned short* __restrict__ t1b, const unsigned short* __restrict__ w2p,
    const float* __restrict__ toff, const float* __restrict__ xres,
    const float* __restrict__ gam, const float* __restrict__ bet,
    const float* __restrict__ mu,  const float* __restrict__ var,
    float* __restrict__ outp)
{
  __shared__ unsigned short Al[128*LSTR];
  __shared__ unsigned short Bl[128*LSTR];
  const int m0   = blockIdx.x * 128;
  const int n0   = blockIdx.y * 128;
  const int t    = threadIdx.x;
  const int lane = t & 63;
  const int wv   = t >> 6;
  const int wm   = (wv & 1) * 64;
  const int wn   = (wv >> 1) * 64;
  const int quad = lane >> 4;
  const int l15  = lane & 15;

  const int apx = t & 127;
  const int gb  = t >> 7;
  const int px  = m0 + apx;
  const int b   = px / NHW, rem = px % NHW;
  const int ho  = rem / NW, wo = rem % NW;

  f32x4 acc[4][4];
  #pragma unroll
  for (int i = 0; i < 4; ++i)
    #pragma unroll
    for (int j = 0; j < 4; ++j) acc[i][j] = (f32x4)(0.f);

  for (int k = 0; k < 9; ++k) {
    const int ky = k/3, kx = k - ky*3;
    // bilinear coeffs once per k, reused for 4 cic rounds
    float offy = toff[(size_t)b*(18*NHW) + k*NHW + rem];
    float offx = toff[(size_t)b*(18*NHW) + (9+k)*NHW + rem];
    float yf = (float)(ho - 1 + ky) + offy;
    float xf = (float)(wo - 1 + kx) + offx;
    float y0f = floorf(yf), x0f = floorf(xf);
    float ty = yf - y0f,   tx = xf - x0f;
    int y0 = (int)y0f, x0 = (int)x0f;
    int y1 = y0 + 1,   x1 = x0 + 1;
    bool vy0 = (y0 >= 0) & (y0 < NH);
    bool vy1 = (y1 >= 0) & (y1 < NH);
    bool vx0 = (x0 >= 0) & (x0 < NW);
    bool vx1 = (x1 >= 0) & (x1 < NW);
    int cy0 = min(max(y0,0),NH-1), cy1 = min(max(y1,0),NH-1);
    int cx0 = min(max(x0,0),NW-1), cx1 = min(max(x1,0),NW-1);
    float wy0 = 1.f - ty, wx0 = 1.f - tx;
    float w00 = (vy0 & vx0) ? wy0*wx0 : 0.f;
    float w01 = (vy0 & vx1) ? wy0*tx  : 0.f;
    float w10 = (vy1 & vx0) ? ty*wx0  : 0.f;
    float w11 = (vy1 & vx1) ? ty*tx   : 0.f;
    const unsigned int rb = (unsigned int)(b*NH);
    const unsigned int o00 = ((rb + cy0)*NW + cx0)*256u;
    const unsigned int o01 = ((rb + cy0)*NW + cx1)*256u;
    const unsigned int o10 = ((rb + cy1)*NW + cx0)*256u;
    const unsigned int o11 = ((rb + cy1)*NW + cx1)*256u;

    for (int cic = 0; cic < 4; ++cic) {
      const int r = k*4 + cic;
      __syncthreads();
      // stage A: 8 bilinear 4-ci tasks (px fixed, groups g = gb+2u)
      #pragma unroll
      for (int u = 0; u < 8; ++u) {
        const int g = gb + 2*u;
        const unsigned int cio = (unsigned int)(cic*64 + g*4);
        uint2 q00 = *(const uint2*)(t1b + o00 + cio);
        uint2 q01 = *(const uint2*)(t1b + o01 + cio);
        uint2 q10 = *(const uint2*)(t1b + o10 + cio);
        uint2 q11 = *(const uint2*)(t1b + o11 + cio);
        float v0 = w00*blo(q00.x) + w01*blo(q01.x) + w10*blo(q10.x) + w11*blo(q11.x);
        float v1 = w00*bhi(q00.x) + w01*bhi(q01.x) + w10*bhi(q10.x) + w11*bhi(q11.x);
        float v2 = w00*blo(q00.y) + w01*blo(q01.y) + w10*blo(q10.y) + w11*blo(q11.y);
        float v3 = w00*bhi(q00.y) + w01*bhi(q01.y) + w10*bhi(q10.y) + w11*bhi(q11.y);
        uint2 o;
        o.x = ((unsigned int)f2b(v1) << 16) | (unsigned int)f2b(v0);
        o.y = ((unsigned int)f2b(v3) << 16) | (unsigned int)f2b(v2);
        *(uint2*)(&Al[apx*LSTR + g*4]) = o;
      }
      // stage B
      #pragma unroll
      for (int u = 0; u < 4; ++u) {
        int tau = t + u*256;
        int row = tau >> 3, seg = tau & 7;
        uint4 q = *(const uint4*)(w2p + (size_t)(n0 + row)*2304 + r*64 + seg*8);
        *(uint4*)(&Bl[row*LSTR + seg*8]) = q;
      }
      __syncthreads();
      #pragma unroll
      for (int kk = 0; kk < 2; ++kk) {
        bf16x8 af[4], bfr[4];
        #pragma unroll
        for (int mt = 0; mt < 4; ++mt)
          af[mt] = *(const bf16x8*)(&Al[(wm + mt*16 + l15)*LSTR + kk*32 + quad*8]);
        #pragma unroll
        for (int nt = 0; nt < 4; ++nt)
          bfr[nt] = *(const bf16x8*)(&Bl[(wn + nt*16 + l15)*LSTR + kk*32 + quad*8]);
        #pragma unroll
        for (int mt = 0; mt < 4; ++mt)
          #pragma unroll
          for (int nt = 0; nt < 4; ++nt)
            acc[mt][nt] = __builtin_amdgcn_mfma_f32_16x16x32_bf16(af[mt], bfr[nt], acc[mt][nt], 0, 0, 0);
      }
    }
  }
  // epilogue: BN + residual + ReLU -> fp32 NCHW (float4 over 4 consecutive px)
  #pragma unroll
  for (int mt = 0; mt < 4; ++mt) {
    const int p4 = m0 + wm + mt*16 + quad*4;
    const int b2 = p4 / NHW, rem2 = p4 % NHW;
    #pragma unroll
    for (int nt = 0; nt < 4; ++nt) {
      const int co = n0 + wn + nt*16 + l15;
      const float inv  = gam[co] * rsqrtf(var[co] + EPSV);
      const float beta = bet[co] - mu[co]*inv;
      const size_t off = (size_t)b2*NCHW + (size_t)co*NHW + rem2;
      float4 res = *(const float4*)(xres + off);
      float4 o;
      o.x = acc[mt][nt][0]*inv + beta + res.x;
      o.y = acc[mt][nt][1]*inv + beta + res.y;
      o.z = acc[mt][nt][2]*inv + beta + res.z;
      o.w = acc[mt][nt][3]*inv + beta + res.w;
      o.x = o.x > 0.f ? o.x : 0.f;
      o.y = o.y > 0.f ? o.y : 0.f;
      o.z = o.z > 0.f ? o.z : 0.f;
      o.w = o.w > 0.f ? o.w : 0.f;
      *(float4*)(outp + off) = o;
    }
  }
}

extern "C" void kernel_launch(void* const* d_in, const int* in_sizes, int n_in,
                              void* d_out, int out_size, void* d_ws, size_t ws_size,
                              hipStream_t stream) {
  const float* x   = (const float*)d_in[0];
  const float* w1  = (const float*)d_in[1];
  const float* g1  = (const float*)d_in[2];
  const float* b1  = (const float*)d_in[3];
  const float* m1  = (const float*)d_in[4];
  const float* v1  = (const float*)d_in[5];
  const float* ow  = (const float*)d_in[6];
  const float* ob  = (const float*)d_in[7];
  const float* w2  = (const float*)d_in[8];
  const float* g2  = (const float*)d_in[9];
  const float* b2  = (const float*)d_in[10];
  const float* m2  = (const float*)d_in[11];
  const float* v2  = (const float*)d_in[12];
  float* out = (float*)d_out;

  // ws layout: xbp 13.78M | t1b 12.85M | toff 1.81M | w1p 1.18M | w2p 1.18M = 30.8MB
  unsigned short* xbp = (unsigned short*)d_ws;                 // 8*58*58*256
  unsigned short* t1b = xbp + (size_t)NB*NHP*NHP*256;
  float*          tof = (float*)(t1b + (size_t)NPIX*256);
  unsigned short* w1p = (unsigned short*)(tof + (size_t)NB*18*NHW);
  unsigned short* w2p = w1p + (size_t)589824;

  hipMemsetAsync(xbp, 0, (size_t)NB*NHP*NHP*256*sizeof(unsigned short), stream);
  prep_x<<<392, 256, 0, stream>>>(x, xbp);
  prep_w<<<2304, 256, 0, stream>>>(w1, w1p);
  prep_w<<<2304, 256, 0, stream>>>(w2, w2p);

  dim3 gg(196, 2, 1);
  gemm_conv1<<<gg, 256, 0, stream>>>(xbp, w1p, g1, b1, m1, v1, t1b);

  hipMemsetAsync(tof, 0, (size_t)NB*18*NHW*sizeof(float), stream);
  dim3 grid2(98, 8, 1);
  offset_conv<<<grid2, 256, 0, stream>>>(t1b, ow, ob, tof);

  gemm_deform<<<gg, 256, 0, stream>>>(t1b, w2p, tof, x, g2, b2, m2, v2, out);
}

// Round 5
// 417.961 us; speedup vs baseline: 1.5038x; 1.5038x over previous
//
#include <hip/hip_runtime.h>

#define NB 8
#define NH 56
#define NW 56
#define NHW 3136          // NH*NW
#define NCHW 802816
#define NPIX 25088        // NB*NHW
#define NHP 58            // padded
#define EPSV 1e-5f

typedef float f32x4 __attribute__((ext_vector_type(4)));
typedef __bf16 bf16x8 __attribute__((ext_vector_type(8)));

__device__ __forceinline__ unsigned short f2b(float f) {
  unsigned int u = __float_as_uint(f);
  u += 0x7FFFu + ((u >> 16) & 1u);
  return (unsigned short)(u >> 16);
}
__device__ __forceinline__ float blo(unsigned int u){ return __uint_as_float(u << 16); }
__device__ __forceinline__ float bhi(unsigned int u){ return __uint_as_float(u & 0xFFFF0000u); }

// XCD-swizzled tile map for 196 M-tiles x 2 N-tiles (both N share A -> same XCD)
__device__ __forceinline__ void tile_map(int bid, int& m0, int& n0) {
  int mT, nT;
  if (bid < 384) { int g = bid >> 4, r = bid & 15; mT = g*8 + (r & 7); nT = r >> 3; }
  else           { int q = bid - 384; mT = 192 + (q >> 1); nT = q & 1; }
  m0 = mT * 128; n0 = nT * 128;
}

// ---------------------------------------------------------------------------
// P1: x NCHW fp32 -> xbp padded NHWC bf16, LDS-tile transpose.
// grid (392 px-tiles, 4 c-tiles), block 256
// ---------------------------------------------------------------------------
__global__ __launch_bounds__(256) void prep_x(
    const float* __restrict__ x, unsigned short* __restrict__ xbp)
{
  __shared__ float T[64][65];
  const int pxt  = blockIdx.x * 64;       // 3136 = 49*64 -> tile never crosses b
  const int cg   = blockIdx.y * 64;
  const int b    = pxt / NHW;
  const int rem0 = pxt % NHW;
  const int t    = threadIdx.x;
  const int pl   = t & 63;
  const int c0   = t >> 6;
  const float* src = x + (size_t)b*NCHW + rem0;
  #pragma unroll
  for (int it = 0; it < 16; ++it) {
    int c = c0 + it*4;
    T[c][pl] = src[(size_t)(cg + c)*NHW + pl];
  }
  __syncthreads();
  const int pr = t >> 5;
  const int cp = t & 31;
  #pragma unroll
  for (int it = 0; it < 8; ++it) {
    int pxl = pr + it*8;
    int rem = rem0 + pxl;
    int ho = rem / NW, wo = rem % NW;
    unsigned int pk = ((unsigned int)f2b(T[cp*2+1][pxl]) << 16) | (unsigned int)f2b(T[cp*2][pxl]);
    *(unsigned int*)(xbp + ((size_t)(b*NHP + ho + 1)*NHP + (wo + 1))*256 + cg + cp*2) = pk;
  }
}

// ---------------------------------------------------------------------------
// P2: w [co][ci][3][3] fp32 -> wp [co][k*256+ci] bf16
// ---------------------------------------------------------------------------
__global__ __launch_bounds__(256) void prep_w(
    const float* __restrict__ w, unsigned short* __restrict__ wp)
{
  int i = blockIdx.x*256 + threadIdx.x;    // 589824 exact
  int co = i / 2304;
  int r  = i % 2304;
  int k  = r >> 8;
  int ci = r & 255;
  wp[i] = f2b(w[((size_t)co*256 + ci)*9 + k]);
}

// ---------------------------------------------------------------------------
// GEMM1: conv3x3 + BN + ReLU -> t1b [px][co] bf16
// BM=128 BN=128 BK=64, 256 thr = 2x2 waves of 64x64; grid 392 (swizzled)
// LDS: 64-short rows, chunk-XOR swizzle (16B aligned, conflict-optimal)
// ---------------------------------------------------------------------------
__global__ __launch_bounds__(256, 2) void gemm_conv1(
    const unsigned short* __restrict__ xbp, const unsigned short* __restrict__ w1p,
    const float* __restrict__ gam, const float* __restrict__ bet,
    const float* __restrict__ mu,  const float* __restrict__ var,
    unsigned short* __restrict__ t1b)
{
  __shared__ unsigned short SMEM[2*128*64];       // Al | Bl, 32 KB
  unsigned short* Al = SMEM;
  unsigned short* Bl = SMEM + 128*64;

  int m0, n0; tile_map(blockIdx.x, m0, n0);
  const int t    = threadIdx.x;
  const int lane = t & 63;
  const int wv   = t >> 6;
  const int wm   = (wv & 1) * 64;
  const int wn   = (wv >> 1) * 64;
  const int quad = lane >> 4;
  const int l15  = lane & 15;

  // staging identity: (row = t>>3 (+32u), seg = t&7) -> 8 lanes = 128B contiguous
  const int srow = t >> 3;
  const int seg  = t & 7;
  const int sxor = (srow & 7);            // row&7 invariant across u (+32u)
  unsigned int pb[4];
  #pragma unroll
  for (int u = 0; u < 4; ++u) {
    int px = m0 + srow + 32*u;
    int b = px / NHW, rem = px % NHW;
    int ho = rem / NW, wo = rem % NW;
    pb[u] = ((unsigned int)(b*NHP + ho)*NHP + wo)*256u;
  }

  f32x4 acc[4][4];
  #pragma unroll
  for (int i = 0; i < 4; ++i)
    #pragma unroll
    for (int j = 0; j < 4; ++j) acc[i][j] = (f32x4)(0.f);

  for (int r = 0; r < 36; ++r) {
    const int k = r >> 2, cic = r & 3;
    const int ky = k/3, kx = k - ky*3;
    const unsigned int tapoff = (unsigned int)((ky*NHP + kx)*256 + cic*64 + seg*8);
    __syncthreads();
    #pragma unroll
    for (int u = 0; u < 4; ++u) {       // A: 128 rows x 64 ci
      uint4 q = *(const uint4*)(xbp + pb[u] + tapoff);
      *(uint4*)(&Al[(srow + 32*u)*64 + ((seg ^ sxor)*8)]) = q;
    }
    #pragma unroll
    for (int u = 0; u < 4; ++u) {       // B: 128 rows x 64 k-slice
      int row = srow + 32*u;
      uint4 q = *(const uint4*)(w1p + (size_t)(n0 + row)*2304 + r*64 + seg*8);
      *(uint4*)(&Bl[row*64 + ((seg ^ sxor)*8)]) = q;
    }
    __syncthreads();
    #pragma unroll
    for (int kk = 0; kk < 2; ++kk) {
      const int c8 = kk*4 + quad;
      bf16x8 af[4], bfr[4];
      #pragma unroll
      for (int mt = 0; mt < 4; ++mt)
        af[mt] = *(const bf16x8*)(&Al[(wm + mt*16 + l15)*64 + ((c8 ^ (l15 & 7))*8)]);
      #pragma unroll
      for (int nt = 0; nt < 4; ++nt)
        bfr[nt] = *(const bf16x8*)(&Bl[(wn + nt*16 + l15)*64 + ((c8 ^ (l15 & 7))*8)]);
      #pragma unroll
      for (int mt = 0; mt < 4; ++mt)
        #pragma unroll
        for (int nt = 0; nt < 4; ++nt)
          acc[mt][nt] = __builtin_amdgcn_mfma_f32_16x16x32_bf16(af[mt], bfr[nt], acc[mt][nt], 0, 0, 0);
    }
  }

  // epilogue: BN+ReLU -> bf16 bounce tile (per-wave region) -> uint4 stores
  __syncthreads();
  unsigned short* Sw = SMEM + wv*4096;       // 64px x 64co shorts
  #pragma unroll
  for (int nt = 0; nt < 4; ++nt) {
    const int co = n0 + wn + nt*16 + l15;
    const float inv  = gam[co] * rsqrtf(var[co] + EPSV);
    const float beta = bet[co] - mu[co]*inv;
    const int chunk = nt*2 + (l15 >> 3);
    #pragma unroll
    for (int mt = 0; mt < 4; ++mt) {
      #pragma unroll
      for (int rr = 0; rr < 4; ++rr) {
        const int pxl = mt*16 + quad*4 + rr;
        float val = acc[mt][nt][rr]*inv + beta;
        val = val > 0.f ? val : 0.f;
        Sw[pxl*64 + ((chunk ^ (pxl & 7))*8) + (l15 & 7)] = f2b(val);
      }
    }
  }
  const int rc8 = lane & 7;
  #pragma unroll
  for (int i = 0; i < 8; ++i) {
    const int pxl = (lane >> 3) + 8*i;
    uint4 q = *(const uint4*)(&Sw[pxl*64 + ((rc8 ^ (pxl & 7))*8)]);
    *(uint4*)(t1b + (size_t)(m0 + wm + pxl)*256 + n0 + wn + rc8*8) = q;
  }
}

// ---------------------------------------------------------------------------
// K2: toff += conv3x3(t1b, off_w) (+off_b on chunk 0); toff pre-zeroed
// ---------------------------------------------------------------------------
__global__ __launch_bounds__(256) void offset_conv(
    const unsigned short* __restrict__ t1b, const float* __restrict__ ow,
    const float* __restrict__ ob, float* __restrict__ toff)
{
  const int p = blockIdx.x*256 + threadIdx.x;
  const int cichunk = blockIdx.y * 32;
  const int b  = p / NHW, rem = p % NHW;
  const int ho = rem / NW, wo = rem % NW;

  float acc[18];
  if (blockIdx.y == 0) {
    #pragma unroll
    for (int c = 0; c < 18; ++c) acc[c] = ob[c];
  } else {
    #pragma unroll
    for (int c = 0; c < 18; ++c) acc[c] = 0.f;
  }

  #pragma unroll
  for (int ky = 0; ky < 3; ++ky) {
    int y = ho - 1 + ky;
    if (y < 0 || y >= NH) continue;
    #pragma unroll
    for (int kx = 0; kx < 3; ++kx) {
      int xx = wo - 1 + kx;
      if (xx < 0 || xx >= NW) continue;
      const int k = ky*3 + kx;
      const unsigned short* base = t1b + ((size_t)(b*NH + y)*NW + xx)*256 + cichunk;
      for (int q = 0; q < 8; ++q) {
        uint2 u = *(const uint2*)(base + q*4);
        float f0 = blo(u.x), f1 = bhi(u.x), f2v = blo(u.y), f3 = bhi(u.y);
        const int ci = cichunk + q*4;
        #pragma unroll
        for (int c = 0; c < 18; ++c) {
          const float* wr = ow + ((size_t)c*256 + ci)*9 + k;   // uniform -> s_load
          acc[c] += f0*wr[0] + f1*wr[9] + f2v*wr[18] + f3*wr[27];
        }
      }
    }
  }
  float* od = toff + (size_t)b*(18*NHW) + rem;
  #pragma unroll
  for (int c = 0; c < 18; ++c)
    atomicAdd(od + c*NHW, acc[c]);
}

// ---------------------------------------------------------------------------
// GEMM2: deform_conv + BN + residual + ReLU -> out NCHW fp32
// same tile shape as GEMM1; A staged via coalesced 4-corner bilinear
// ---------------------------------------------------------------------------
__global__ __launch_bounds__(256, 2) void gemm_deform(
    const unsigned short* __restrict__ t1b, const unsigned short* __restrict__ w2p,
    const float* __restrict__ toff, const float* __restrict__ xres,
    const float* __restrict__ gam, const float* __restrict__ bet,
    const float* __restrict__ mu,  const float* __restrict__ var,
    float* __restrict__ outp)
{
  __shared__ unsigned short SMEM[2*128*64];
  unsigned short* Al = SMEM;
  unsigned short* Bl = SMEM + 128*64;

  int m0, n0; tile_map(blockIdx.x, m0, n0);
  const int t    = threadIdx.x;
  const int lane = t & 63;
  const int wv   = t >> 6;
  const int wm   = (wv & 1) * 64;
  const int wn   = (wv >> 1) * 64;
  const int quad = lane >> 4;
  const int l15  = lane & 15;

  const int srow = t >> 3;
  const int seg  = t & 7;
  const int sxor = (srow & 7);
  int hoU[4], woU[4], obU[4];
  #pragma unroll
  for (int u = 0; u < 4; ++u) {
    int px = m0 + srow + 32*u;
    int b = px / NHW, rem = px % NHW;
    hoU[u] = rem / NW; woU[u] = rem % NW;
    obU[u] = b*(18*NHW) + rem;
  }

  f32x4 acc[4][4];
  #pragma unroll
  for (int i = 0; i < 4; ++i)
    #pragma unroll
    for (int j = 0; j < 4; ++j) acc[i][j] = (f32x4)(0.f);

  for (int k = 0; k < 9; ++k) {
    const int ky = k/3, kx = k - ky*3;
    unsigned int o00[4], o01[4], o10[4], o11[4];
    float cw0[4], cw1[4], cw2[4], cw3[4];
    #pragma unroll
    for (int u = 0; u < 4; ++u) {
      float offy = toff[obU[u] + k*NHW];
      float offx = toff[obU[u] + (9+k)*NHW];
      float yf = (float)(hoU[u] - 1 + ky) + offy;
      float xf = (float)(woU[u] - 1 + kx) + offx;
      float y0f = floorf(yf), x0f = floorf(xf);
      float ty = yf - y0f,   tx = xf - x0f;
      int y0 = (int)y0f, x0 = (int)x0f;
      int y1 = y0 + 1,   x1 = x0 + 1;
      bool vy0 = (y0 >= 0) & (y0 < NH);
      bool vy1 = (y1 >= 0) & (y1 < NH);
      bool vx0 = (x0 >= 0) & (x0 < NW);
      bool vx1 = (x1 >= 0) & (x1 < NW);
      int cy0 = min(max(y0,0),NH-1), cy1 = min(max(y1,0),NH-1);
      int cx0 = min(max(x0,0),NW-1), cx1 = min(max(x1,0),NW-1);
      float wy0 = 1.f - ty, wx0 = 1.f - tx;
      cw0[u] = (vy0 & vx0) ? wy0*wx0 : 0.f;
      cw1[u] = (vy0 & vx1) ? wy0*tx  : 0.f;
      cw2[u] = (vy1 & vx0) ? ty*wx0  : 0.f;
      cw3[u] = (vy1 & vx1) ? ty*tx   : 0.f;
      const unsigned int rb = (unsigned int)((obU[u]/(18*NHW))*NH);
      o00[u] = ((rb + cy0)*NW + cx0)*256u;
      o01[u] = ((rb + cy0)*NW + cx1)*256u;
      o10[u] = ((rb + cy1)*NW + cx0)*256u;
      o11[u] = ((rb + cy1)*NW + cx1)*256u;
    }

    for (int cic = 0; cic < 4; ++cic) {
      const int r = k*4 + cic;
      const unsigned int cio = (unsigned int)(cic*64 + seg*8);
      __syncthreads();
      #pragma unroll
      for (int u = 0; u < 4; ++u) {     // A: bilinear of 4 coalesced corner reads
        uint4 q00 = *(const uint4*)(t1b + o00[u] + cio);
        uint4 q01 = *(const uint4*)(t1b + o01[u] + cio);
        uint4 q10 = *(const uint4*)(t1b + o10[u] + cio);
        uint4 q11 = *(const uint4*)(t1b + o11[u] + cio);
        const float w00 = cw0[u], w01 = cw1[u], w10 = cw2[u], w11 = cw3[u];
        uint4 res;
        {
          float a = w00*blo(q00.x) + w01*blo(q01.x) + w10*blo(q10.x) + w11*blo(q11.x);
          float bqq = w00*bhi(q00.x) + w01*bhi(q01.x) + w10*bhi(q10.x) + w11*bhi(q11.x);
          res.x = ((unsigned int)f2b(bqq) << 16) | (unsigned int)f2b(a);
        }
        {
          float a = w00*blo(q00.y) + w01*blo(q01.y) + w10*blo(q10.y) + w11*blo(q11.y);
          float bqq = w00*bhi(q00.y) + w01*bhi(q01.y) + w10*bhi(q10.y) + w11*bhi(q11.y);
          res.y = ((unsigned int)f2b(bqq) << 16) | (unsigned int)f2b(a);
        }
        {
          float a = w00*blo(q00.z) + w01*blo(q01.z) + w10*blo(q10.z) + w11*blo(q11.z);
          float bqq = w00*bhi(q00.z) + w01*bhi(q01.z) + w10*bhi(q10.z) + w11*bhi(q11.z);
          res.z = ((unsigned int)f2b(bqq) << 16) | (unsigned int)f2b(a);
        }
        {
          float a = w00*blo(q00.w) + w01*blo(q01.w) + w10*blo(q10.w) + w11*blo(q11.w);
          float bqq = w00*bhi(q00.w) + w01*bhi(q01.w) + w10*bhi(q10.w) + w11*bhi(q11.w);
          res.w = ((unsigned int)f2b(bqq) << 16) | (unsigned int)f2b(a);
        }
        *(uint4*)(&Al[(srow + 32*u)*64 + ((seg ^ sxor)*8)]) = res;
      }
      #pragma unroll
      for (int u = 0; u < 4; ++u) {     // B
        int row = srow + 32*u;
        uint4 q = *(const uint4*)(w2p + (size_t)(n0 + row)*2304 + r*64 + seg*8);
        *(uint4*)(&Bl[row*64 + ((seg ^ sxor)*8)]) = q;
      }
      __syncthreads();
      #pragma unroll
      for (int kk = 0; kk < 2; ++kk) {
        const int c8 = kk*4 + quad;
        bf16x8 af[4], bfr[4];
        #pragma unroll
        for (int mt = 0; mt < 4; ++mt)
          af[mt] = *(const bf16x8*)(&Al[(wm + mt*16 + l15)*64 + ((c8 ^ (l15 & 7))*8)]);
        #pragma unroll
        for (int nt = 0; nt < 4; ++nt)
          bfr[nt] = *(const bf16x8*)(&Bl[(wn + nt*16 + l15)*64 + ((c8 ^ (l15 & 7))*8)]);
        #pragma unroll
        for (int mt = 0; mt < 4; ++mt)
          #pragma unroll
          for (int nt = 0; nt < 4; ++nt)
            acc[mt][nt] = __builtin_amdgcn_mfma_f32_16x16x32_bf16(af[mt], bfr[nt], acc[mt][nt], 0, 0, 0);
      }
    }
  }

  // epilogue: f32 bounce (per-wave region, 2 halves) -> coalesced NCHW
  __syncthreads();
  float* Sl = (float*)SMEM;
  const int wb = wv*2048;
  const int pxg = m0 + wm + lane;
  const int bo  = pxg / NHW, remo = pxg % NHW;
  const size_t obase = (size_t)bo*NCHW + remo;
  #pragma unroll
  for (int h = 0; h < 2; ++h) {
    #pragma unroll
    for (int mt = 0; mt < 4; ++mt) {
      #pragma unroll
      for (int nt2 = 0; nt2 < 2; ++nt2) {
        const int nt = h*2 + nt2;
        const int co_l = nt2*16 + l15;
        #pragma unroll
        for (int rr = 0; rr < 4; ++rr) {
          const int pxl = mt*16 + quad*4 + rr;
          Sl[wb + pxl*32 + (co_l ^ (pxl & 31))] = acc[mt][nt][rr];
        }
      }
    }
    #pragma unroll
    for (int co_l = 0; co_l < 32; ++co_l) {
      const int co = n0 + wn + h*32 + co_l;
      const float inv  = gam[co] * rsqrtf(var[co] + EPSV);
      const float beta = bet[co] - mu[co]*inv;
      const size_t off = obase + (size_t)co*NHW;
      float val = Sl[wb + lane*32 + (co_l ^ (lane & 31))];
      float o = val*inv + beta + xres[off];
      outp[off] = o > 0.f ? o : 0.f;
    }
  }
}

extern "C" void kernel_launch(void* const* d_in, const int* in_sizes, int n_in,
                              void* d_out, int out_size, void* d_ws, size_t ws_size,
                              hipStream_t stream) {
  const float* x   = (const float*)d_in[0];
  const float* w1  = (const float*)d_in[1];
  const float* g1  = (const float*)d_in[2];
  const float* b1  = (const float*)d_in[3];
  const float* m1  = (const float*)d_in[4];
  const float* v1  = (const float*)d_in[5];
  const float* ow  = (const float*)d_in[6];
  const float* ob  = (const float*)d_in[7];
  const float* w2  = (const float*)d_in[8];
  const float* g2  = (const float*)d_in[9];
  const float* b2  = (const float*)d_in[10];
  const float* m2  = (const float*)d_in[11];
  const float* v2  = (const float*)d_in[12];
  float* out = (float*)d_out;

  // ws layout: xbp 13.78M | t1b 12.85M | toff 1.81M | w1p 1.18M | w2p 1.18M = 30.8MB
  unsigned short* xbp = (unsigned short*)d_ws;
  unsigned short* t1b = xbp + (size_t)NB*NHP*NHP*256;
  float*          tof = (float*)(t1b + (size_t)NPIX*256);
  unsigned short* w1p = (unsigned short*)(tof + (size_t)NB*18*NHW);
  unsigned short* w2p = w1p + (size_t)589824;

  hipMemsetAsync(xbp, 0, (size_t)NB*NHP*NHP*256*sizeof(unsigned short), stream);
  dim3 gp(392, 4, 1);
  prep_x<<<gp, 256, 0, stream>>>(x, xbp);
  prep_w<<<2304, 256, 0, stream>>>(w1, w1p);
  prep_w<<<2304, 256, 0, stream>>>(w2, w2p);

  gemm_conv1<<<392, 256, 0, stream>>>(xbp, w1p, g1, b1, m1, v1, t1b);

  hipMemsetAsync(tof, 0, (size_t)NB*18*NHW*sizeof(float), stream);
  dim3 grid2(98, 8, 1);
  offset_conv<<<grid2, 256, 0, stream>>>(t1b, ow, ob, tof);

  gemm_deform<<<392, 256, 0, stream>>>(t1b, w2p, tof, x, g2, b2, m2, v2, out);
}

// Round 6
// 263.479 us; speedup vs baseline: 2.3855x; 1.5863x over previous
//
#include <hip/hip_runtime.h>

#define NB 8
#define NH 56
#define NW 56
#define NHW 3136          // NH*NW
#define NCHW 802816
#define NPIX 25088        // NB*NHW
#define NHP 58            // padded dim
#define EPSV 1e-5f

typedef float f32x4 __attribute__((ext_vector_type(4)));
typedef __bf16 bf16x8 __attribute__((ext_vector_type(8)));

__device__ __forceinline__ unsigned short f2b(float f) {   // RNE (epilogues)
  unsigned int u = __float_as_uint(f);
  u += 0x7FFFu + ((u >> 16) & 1u);
  return (unsigned short)(u >> 16);
}
__device__ __forceinline__ float blo(unsigned int u){ return __uint_as_float(u << 16); }
__device__ __forceinline__ float bhi(unsigned int u){ return __uint_as_float(u & 0xFFFF0000u); }
// pack 2 fp32 -> 2 bf16 (truncation) in ONE v_perm
__device__ __forceinline__ unsigned int pack_trunc(float f0, float f1) {
  return __builtin_amdgcn_perm(__float_as_uint(f1), __float_as_uint(f0), 0x07060302u);
}

// ---------------------------------------------------------------------------
// P1: x NCHW fp32 -> xbp padded NHWC bf16 (58x58, border zeroed by memset)
// ---------------------------------------------------------------------------
__global__ __launch_bounds__(256) void prep_x(
    const float* __restrict__ x, unsigned short* __restrict__ xbp)
{
  __shared__ float T[64][65];
  const int pxt  = blockIdx.x * 64;       // 3136 = 49*64 -> never crosses b
  const int cg   = blockIdx.y * 64;
  const int b    = pxt / NHW;
  const int rem0 = pxt % NHW;
  const int t    = threadIdx.x;
  const int pl   = t & 63;
  const int c0   = t >> 6;
  const float* src = x + (size_t)b*NCHW + rem0;
  #pragma unroll
  for (int it = 0; it < 16; ++it) {
    int c = c0 + it*4;
    T[c][pl] = src[(size_t)(cg + c)*NHW + pl];
  }
  __syncthreads();
  const int pr = t >> 5;
  const int cp = t & 31;
  #pragma unroll
  for (int it = 0; it < 8; ++it) {
    int pxl = pr + it*8;
    int rem = rem0 + pxl;
    int ho = rem / NW, wo = rem % NW;
    unsigned int pk = ((unsigned int)f2b(T[cp*2+1][pxl]) << 16) | (unsigned int)f2b(T[cp*2][pxl]);
    *(unsigned int*)(xbp + ((size_t)(b*NHP + ho + 1)*NHP + (wo + 1))*256 + cg + cp*2) = pk;
  }
}

// ---------------------------------------------------------------------------
// P2: w [co][ci][3][3] fp32 -> wp [co][k*256+ci] bf16
// ---------------------------------------------------------------------------
__global__ __launch_bounds__(256) void prep_w(
    const float* __restrict__ w, unsigned short* __restrict__ wp)
{
  int i = blockIdx.x*256 + threadIdx.x;    // 589824 exact
  int co = i / 2304;
  int r  = i % 2304;
  int k  = r >> 8;
  int ci = r & 255;
  wp[i] = f2b(w[((size_t)co*256 + ci)*9 + k]);
}

// P3: off_w [18][256][3][3] -> w3p [32 rows][k*256+ci] bf16, rows 18..31 = 0
__global__ __launch_bounds__(256) void prep_w3(
    const float* __restrict__ ow, unsigned short* __restrict__ w3p)
{
  int i = blockIdx.x*256 + threadIdx.x;    // 32*2304 = 73728 exact
  int co = i / 2304;
  int r  = i % 2304;
  int k  = r >> 8;
  int ci = r & 255;
  w3p[i] = (co < 18) ? f2b(ow[((size_t)co*256 + ci)*9 + k]) : (unsigned short)0;
}

// ---------------------------------------------------------------------------
// GEMM1: conv3x3 + BN + ReLU -> t1b padded NHWC bf16
// BM=64 BN=256 BK=64, 512 thr = 8 waves (2M x 4N), wave tile 32x64
// grid 392; LDS: A 8KB + B 32KB = 40KB
// ---------------------------------------------------------------------------
__global__ __launch_bounds__(512, 4) void gemm_conv1(
    const unsigned short* __restrict__ xbp, const unsigned short* __restrict__ w1p,
    const float* __restrict__ gam, const float* __restrict__ bet,
    const float* __restrict__ mu,  const float* __restrict__ var,
    unsigned short* __restrict__ t1b)
{
  __shared__ unsigned short SMEM[20480];     // Al 4096 | Bl 16384
  unsigned short* Al = SMEM;
  unsigned short* Bl = SMEM + 4096;

  const int m0   = blockIdx.x * 64;
  const int t    = threadIdx.x;
  const int lane = t & 63;
  const int wv   = t >> 6;
  const int wvM  = wv & 1;
  const int wvN  = wv >> 1;
  const int quad = lane >> 4;
  const int l15  = lane & 15;

  const int srow = t >> 3;     // 0..63
  const int seg  = t & 7;
  {
  }
  const int px  = m0 + srow;
  const int b   = px / NHW, rem = px % NHW;
  const int ho  = rem / NW, wo = rem % NW;
  const unsigned int pbase = ((unsigned int)(b*NHP + ho)*NHP + wo)*256u;

  f32x4 acc[2][4];
  #pragma unroll
  for (int i = 0; i < 2; ++i)
    #pragma unroll
    for (int j = 0; j < 4; ++j) acc[i][j] = (f32x4)(0.f);

  for (int r = 0; r < 36; ++r) {
    const int k = r >> 2, cic = r & 3;
    const int ky = k/3, kx = k - ky*3;
    __syncthreads();
    {   // A: 1 uint4 per thread
      uint4 q = *(const uint4*)(xbp + pbase + (unsigned int)((ky*NHP + kx)*256 + cic*64 + seg*8));
      *(uint4*)(&Al[srow*64 + ((seg ^ (srow & 7))*8)]) = q;
    }
    #pragma unroll
    for (int u = 0; u < 4; ++u) {   // B: 4 uint4 per thread
      int tau = t + u*512;
      int row = tau >> 3, sb = tau & 7;
      uint4 q = *(const uint4*)(w1p + (size_t)row*2304 + r*64 + sb*8);
      *(uint4*)(&Bl[row*64 + ((sb ^ (row & 7))*8)]) = q;
    }
    __syncthreads();
    #pragma unroll
    for (int kk = 0; kk < 2; ++kk) {
      const int s8 = (kk*4 + quad) ^ (l15 & 7);
      bf16x8 af[2], bfr[4];
      #pragma unroll
      for (int mt = 0; mt < 2; ++mt)
        af[mt] = *(const bf16x8*)(&Al[(wvM*32 + mt*16 + l15)*64 + s8*8]);
      #pragma unroll
      for (int nt = 0; nt < 4; ++nt)
        bfr[nt] = *(const bf16x8*)(&Bl[(wvN*64 + nt*16 + l15)*64 + s8*8]);
      #pragma unroll
      for (int mt = 0; mt < 2; ++mt)
        #pragma unroll
        for (int nt = 0; nt < 4; ++nt)
          acc[mt][nt] = __builtin_amdgcn_mfma_f32_16x16x32_bf16(af[mt], bfr[nt], acc[mt][nt], 0, 0, 0);
    }
  }

  // epilogue: BN+ReLU -> per-wave bounce (32px x 72 shorts) -> padded t1b
  __syncthreads();
  unsigned short* Sw = SMEM + wv*2304;
  #pragma unroll
  for (int nt = 0; nt < 4; ++nt) {
    const int co = wvN*64 + nt*16 + l15;
    const float inv  = gam[co] * rsqrtf(var[co] + EPSV);
    const float beta = bet[co] - mu[co]*inv;
    #pragma unroll
    for (int mt = 0; mt < 2; ++mt) {
      #pragma unroll
      for (int rr = 0; rr < 4; ++rr) {
        const int pxl = mt*16 + quad*4 + rr;
        float val = acc[mt][nt][rr]*inv + beta;
        val = val > 0.f ? val : 0.f;
        Sw[pxl*72 + nt*16 + l15] = f2b(val);
      }
    }
  }
  // wave-synchronous read-out: 4 iters x (8 px x 8 segs)
  #pragma unroll
  for (int i = 0; i < 4; ++i) {
    const int pxl = (lane >> 3) + 8*i;
    const int sc  = lane & 7;
    uint4 q = *(const uint4*)(&Sw[pxl*72 + sc*8]);
    const int pg = m0 + wvM*32 + pxl;
    const int bb = pg / NHW, rm = pg % NHW;
    const int hh = rm / NW, ww = rm % NW;
    *(uint4*)(t1b + ((size_t)(bb*NHP + hh + 1)*NHP + ww + 1)*256 + wvN*64 + sc*8) = q;
  }
}

// ---------------------------------------------------------------------------
// GEMM-OFF: offset conv as MFMA GEMM, N=32 (18 real + 14 zero rows)
// BM=64 BK=64, 256 thr = 4 waves, wave tile 16x32; writes toff directly
// ---------------------------------------------------------------------------
__global__ __launch_bounds__(256, 4) void gemm_off(
    const unsigned short* __restrict__ t1b, const unsigned short* __restrict__ w3p,
    const float* __restrict__ ob, float* __restrict__ toff)
{
  __shared__ unsigned short Al[4096];   // 64x64
  __shared__ unsigned short Bl[2048];   // 32x64

  const int m0   = blockIdx.x * 64;
  const int t    = threadIdx.x;
  const int lane = t & 63;
  const int wv   = t >> 6;
  const int quad = lane >> 4;
  const int l15  = lane & 15;

  const int arow = t >> 2;      // 0..63
  const int as4  = t & 3;
  const int pxa  = m0 + arow;
  const int ba   = pxa / NHW, rema = pxa % NHW;
  const unsigned int pbase = ((unsigned int)(ba*NHP + rema/NW)*NHP + rema%NW)*256u;

  const int brow = t >> 3;      // 0..31
  const int bs   = t & 7;

  f32x4 acc[2];
  acc[0] = (f32x4)(0.f); acc[1] = (f32x4)(0.f);

  for (int r = 0; r < 36; ++r) {
    const int k = r >> 2, cic = r & 3;
    const int ky = k/3, kx = k - ky*3;
    __syncthreads();
    #pragma unroll
    for (int u = 0; u < 2; ++u) {
      const int sg = as4 + 4*u;
      uint4 q = *(const uint4*)(t1b + pbase + (unsigned int)((ky*NHP + kx)*256 + cic*64 + sg*8));
      *(uint4*)(&Al[arow*64 + ((sg ^ (arow & 7))*8)]) = q;
    }
    {
      uint4 q = *(const uint4*)(w3p + (size_t)brow*2304 + r*64 + bs*8);
      *(uint4*)(&Bl[brow*64 + ((bs ^ (brow & 7))*8)]) = q;
    }
    __syncthreads();
    #pragma unroll
    for (int kk = 0; kk < 2; ++kk) {
      const int s8 = (kk*4 + quad) ^ (l15 & 7);
      bf16x8 af = *(const bf16x8*)(&Al[(wv*16 + l15)*64 + s8*8]);
      #pragma unroll
      for (int nt = 0; nt < 2; ++nt) {
        bf16x8 bfr = *(const bf16x8*)(&Bl[(nt*16 + l15)*64 + s8*8]);
        acc[nt] = __builtin_amdgcn_mfma_f32_16x16x32_bf16(af, bfr, acc[nt], 0, 0, 0);
      }
    }
  }
  #pragma unroll
  for (int nt = 0; nt < 2; ++nt) {
    const int co = nt*16 + l15;
    if (co < 18) {
      const float bias = ob[co];
      #pragma unroll
      for (int rr = 0; rr < 4; ++rr) {
        const int pg = m0 + wv*16 + quad*4 + rr;
        const int bb = pg / NHW, rm = pg % NHW;
        toff[(size_t)bb*(18*NHW) + (size_t)co*NHW + rm] = acc[nt][rr] + bias;
      }
    }
  }
}

// ---------------------------------------------------------------------------
// GEMM2: deform_conv + BN + residual + ReLU -> out NCHW fp32
// BM=64 BN=256 BK=64, 512 thr; padded t1b => maskless bilinear, perm-trunc pack
// ---------------------------------------------------------------------------
__global__ __launch_bounds__(512, 4) void gemm_deform(
    const unsigned short* __restrict__ t1b, const unsigned short* __restrict__ w2p,
    const float* __restrict__ toff, const float* __restrict__ xres,
    const float* __restrict__ gam, const float* __restrict__ bet,
    const float* __restrict__ mu,  const float* __restrict__ var,
    float* __restrict__ outp)
{
  __shared__ unsigned short SMEM[20480];     // Al 4096 | Bl 16384
  unsigned short* Al = SMEM;
  unsigned short* Bl = SMEM + 4096;

  const int m0   = blockIdx.x * 64;
  const int t    = threadIdx.x;
  const int lane = t & 63;
  const int wv   = t >> 6;
  const int wvM  = wv & 1;
  const int wvN  = wv >> 1;
  const int quad = lane >> 4;
  const int l15  = lane & 15;

  const int srow = t >> 3;     // 0..63
  const int seg  = t & 7;
  const int px   = m0 + srow;
  const int b    = px / NHW, rem = px % NHW;
  const int ho   = rem / NW, wo = rem % NW;
  const int obb  = b*(18*NHW) + rem;
  const unsigned int prowb = (unsigned int)(b*NHP);

  f32x4 acc[2][4];
  #pragma unroll
  for (int i = 0; i < 2; ++i)
    #pragma unroll
    for (int j = 0; j < 4; ++j) acc[i][j] = (f32x4)(0.f);

  for (int k = 0; k < 9; ++k) {
    const int ky = k/3, kx = k - ky*3;
    // maskless bilinear coords in padded space (pad rows are zeros)
    const float offy = toff[obb + k*NHW];
    const float offx = toff[obb + (9+k)*NHW];
    const float yf = (float)(ho - 1 + ky) + offy;
    const float xf = (float)(wo - 1 + kx) + offx;
    const float y0f = floorf(yf), x0f = floorf(xf);
    const float ty = yf - y0f,   tx = xf - x0f;
    const int y0p = (int)y0f + 1, x0p = (int)x0f + 1;
    const int cy0 = min(max(y0p,   0), NHP-1);
    const int cy1 = min(max(y0p+1, 0), NHP-1);
    const int cx0 = min(max(x0p,   0), NHP-1);
    const int cx1 = min(max(x0p+1, 0), NHP-1);
    const float w00 = (1.f-ty)*(1.f-tx);
    const float w01 = (1.f-ty)*tx;
    const float w10 = ty*(1.f-tx);
    const float w11 = ty*tx;
    const unsigned int o00 = ((prowb + cy0)*NHP + cx0)*256u + seg*8u;
    const unsigned int o01 = ((prowb + cy0)*NHP + cx1)*256u + seg*8u;
    const unsigned int o10 = ((prowb + cy1)*NHP + cx0)*256u + seg*8u;
    const unsigned int o11 = ((prowb + cy1)*NHP + cx1)*256u + seg*8u;

    for (int cic = 0; cic < 4; ++cic) {
      const int r = k*4 + cic;
      __syncthreads();
      {   // A: bilinear of 4 coalesced corner uint4 loads, perm-trunc pack
        const unsigned int cio = (unsigned int)(cic*64);
        uint4 q00 = *(const uint4*)(t1b + o00 + cio);
        uint4 q01 = *(const uint4*)(t1b + o01 + cio);
        uint4 q10 = *(const uint4*)(t1b + o10 + cio);
        uint4 q11 = *(const uint4*)(t1b + o11 + cio);
        uint4 res;
        {
          float a0 = w00*blo(q00.x) + w01*blo(q01.x) + w10*blo(q10.x) + w11*blo(q11.x);
          float a1 = w00*bhi(q00.x) + w01*bhi(q01.x) + w10*bhi(q10.x) + w11*bhi(q11.x);
          res.x = pack_trunc(a0, a1);
        }
        {
          float a0 = w00*blo(q00.y) + w01*blo(q01.y) + w10*blo(q10.y) + w11*blo(q11.y);
          float a1 = w00*bhi(q00.y) + w01*bhi(q01.y) + w10*bhi(q10.y) + w11*bhi(q11.y);
          res.y = pack_trunc(a0, a1);
        }
        {
          float a0 = w00*blo(q00.z) + w01*blo(q01.z) + w10*blo(q10.z) + w11*blo(q11.z);
          float a1 = w00*bhi(q00.z) + w01*bhi(q01.z) + w10*bhi(q10.z) + w11*bhi(q11.z);
          res.z = pack_trunc(a0, a1);
        }
        {
          float a0 = w00*blo(q00.w) + w01*blo(q01.w) + w10*blo(q10.w) + w11*blo(q11.w);
          float a1 = w00*bhi(q00.w) + w01*bhi(q01.w) + w10*bhi(q10.w) + w11*bhi(q11.w);
          res.w = pack_trunc(a0, a1);
        }
        *(uint4*)(&Al[srow*64 + ((seg ^ (srow & 7))*8)]) = res;
      }
      #pragma unroll
      for (int u = 0; u < 4; ++u) {   // B
        int tau = t + u*512;
        int row = tau >> 3, sb = tau & 7;
        uint4 q = *(const uint4*)(w2p + (size_t)row*2304 + r*64 + sb*8);
        *(uint4*)(&Bl[row*64 + ((sb ^ (row & 7))*8)]) = q;
      }
      __syncthreads();
      #pragma unroll
      for (int kk = 0; kk < 2; ++kk) {
        const int s8 = (kk*4 + quad) ^ (l15 & 7);
        bf16x8 af[2], bfr[4];
        #pragma unroll
        for (int mt = 0; mt < 2; ++mt)
          af[mt] = *(const bf16x8*)(&Al[(wvM*32 + mt*16 + l15)*64 + s8*8]);
        #pragma unroll
        for (int nt = 0; nt < 4; ++nt)
          bfr[nt] = *(const bf16x8*)(&Bl[(wvN*64 + nt*16 + l15)*64 + s8*8]);
        #pragma unroll
        for (int mt = 0; mt < 2; ++mt)
          #pragma unroll
          for (int nt = 0; nt < 4; ++nt)
            acc[mt][nt] = __builtin_amdgcn_mfma_f32_16x16x32_bf16(af[mt], bfr[nt], acc[mt][nt], 0, 0, 0);
      }
    }
  }

  // epilogue: per-wave f32 bounce (32px x 33), 2 co-halves -> coalesced NCHW
  __syncthreads();
  float* Sl = (float*)SMEM + wv*1056;
  const int pxl_r = lane & 31;
  const int csel  = lane >> 5;
  const int pg    = m0 + wvM*32 + pxl_r;
  const int bo    = pg / NHW, remo = pg % NHW;
  const size_t obase = (size_t)bo*NCHW + remo;
  #pragma unroll
  for (int h = 0; h < 2; ++h) {
    #pragma unroll
    for (int nt2 = 0; nt2 < 2; ++nt2) {
      const int nt = h*2 + nt2;
      #pragma unroll
      for (int mt = 0; mt < 2; ++mt) {
        #pragma unroll
        for (int rr = 0; rr < 4; ++rr) {
          const int pxl = mt*16 + quad*4 + rr;
          Sl[pxl*33 + nt2*16 + l15] = acc[mt][nt][rr];
        }
      }
    }
    #pragma unroll
    for (int j = 0; j < 16; ++j) {
      const int col = csel*16 + j;
      const int co  = wvN*64 + h*32 + col;
      const float inv  = gam[co] * rsqrtf(var[co] + EPSV);
      const float beta = bet[co] - mu[co]*inv;
      const size_t off = obase + (size_t)co*NHW;
      float val = Sl[pxl_r*33 + col];
      float o = val*inv + beta + xres[off];
      outp[off] = o > 0.f ? o : 0.f;
    }
  }
}

extern "C" void kernel_launch(void* const* d_in, const int* in_sizes, int n_in,
                              void* d_out, int out_size, void* d_ws, size_t ws_size,
                              hipStream_t stream) {
  const float* x   = (const float*)d_in[0];
  const float* w1  = (const float*)d_in[1];
  const float* g1  = (const float*)d_in[2];
  const float* b1  = (const float*)d_in[3];
  const float* m1  = (const float*)d_in[4];
  const float* v1  = (const float*)d_in[5];
  const float* ow  = (const float*)d_in[6];
  const float* ob  = (const float*)d_in[7];
  const float* w2  = (const float*)d_in[8];
  const float* g2  = (const float*)d_in[9];
  const float* b2  = (const float*)d_in[10];
  const float* m2  = (const float*)d_in[11];
  const float* v2  = (const float*)d_in[12];
  float* out = (float*)d_out;

  const size_t PADSZ = (size_t)NB*NHP*NHP*256;      // 6,889,472 shorts
  unsigned short* xbp = (unsigned short*)d_ws;
  unsigned short* t1b = xbp + PADSZ;
  float*          tof = (float*)(t1b + PADSZ);
  unsigned short* w1p = (unsigned short*)(tof + (size_t)NB*18*NHW);
  unsigned short* w2p = w1p + (size_t)589824;
  unsigned short* w3p = w2p + (size_t)589824;

  // zero both padded buffers in one shot (borders must be 0)
  hipMemsetAsync(xbp, 0, 2*PADSZ*sizeof(unsigned short), stream);

  dim3 gp(392, 4, 1);
  prep_x<<<gp, 256, 0, stream>>>(x, xbp);
  prep_w<<<2304, 256, 0, stream>>>(w1, w1p);
  prep_w<<<2304, 256, 0, stream>>>(w2, w2p);
  prep_w3<<<288, 256, 0, stream>>>(ow, w3p);

  gemm_conv1<<<392, 512, 0, stream>>>(xbp, w1p, g1, b1, m1, v1, t1b);
  gemm_off<<<392, 256, 0, stream>>>(t1b, w3p, ob, tof);
  gemm_deform<<<392, 512, 0, stream>>>(t1b, w2p, tof, x, g2, b2, m2, v2, out);
}

// Round 7
// 255.635 us; speedup vs baseline: 2.4587x; 1.0307x over previous
//
#include <hip/hip_runtime.h>

#define NB 8
#define NH 56
#define NW 56
#define NHW 3136          // NH*NW
#define NCHW 802816
#define NPIX 25088        // NB*NHW
#define NHP 58            // padded dim
#define EPSV 1e-5f

typedef float f32x4 __attribute__((ext_vector_type(4)));
typedef __bf16 bf16x8 __attribute__((ext_vector_type(8)));

__device__ __forceinline__ unsigned short f2b(float f) {   // RNE (epilogues)
  unsigned int u = __float_as_uint(f);
  u += 0x7FFFu + ((u >> 16) & 1u);
  return (unsigned short)(u >> 16);
}
__device__ __forceinline__ float blo(unsigned int u){ return __uint_as_float(u << 16); }
__device__ __forceinline__ float bhi(unsigned int u){ return __uint_as_float(u & 0xFFFF0000u); }
// pack 2 fp32 -> 2 bf16 (truncation) in ONE v_perm
__device__ __forceinline__ unsigned int pack_trunc(float f0, float f1) {
  return __builtin_amdgcn_perm(__float_as_uint(f1), __float_as_uint(f0), 0x07060302u);
}
// barrier WITHOUT vmcnt drain: ds_writes visible (lgkmcnt 0), prefetch loads stay in flight
__device__ __forceinline__ void soft_barrier() {
  __builtin_amdgcn_s_waitcnt(0xC07F);   // vmcnt=63, expcnt=7, lgkmcnt=0
  __builtin_amdgcn_s_barrier();
}

// ---------------------------------------------------------------------------
// P0: zero the 1px borders of xbp and t1b (replaces 27.5MB memset)
// 8*228 border px * 256 ch; 32 uint4-tasks per px; 228 blocks x 256
// ---------------------------------------------------------------------------
__global__ __launch_bounds__(256) void clear_borders(
    unsigned short* __restrict__ xbp, unsigned short* __restrict__ t1b)
{
  int i = blockIdx.x*256 + threadIdx.x;        // 58368 exact
  int q = i & 31; int pid = i >> 5;
  int b = pid / 228, j = pid % 228;
  int y, x;
  if (j < 58)       { y = 0;  x = j; }
  else if (j < 116) { y = 57; x = j - 58; }
  else { int jj = j - 116; y = 1 + (jj >> 1); x = (jj & 1) * 57; }
  size_t addr = ((size_t)(b*NHP + y)*NHP + x)*256 + q*8;
  uint4 z = make_uint4(0u,0u,0u,0u);
  *(uint4*)(xbp + addr) = z;
  *(uint4*)(t1b + addr) = z;
}

// ---------------------------------------------------------------------------
// P1: x NCHW fp32 -> xbp padded NHWC bf16 (interior only; borders cleared by P0)
// ---------------------------------------------------------------------------
__global__ __launch_bounds__(256) void prep_x(
    const float* __restrict__ x, unsigned short* __restrict__ xbp)
{
  __shared__ float T[64][65];
  const int pxt  = blockIdx.x * 64;       // never crosses b (3136 = 49*64)
  const int cg   = blockIdx.y * 64;
  const int b    = pxt / NHW;
  const int rem0 = pxt % NHW;
  const int t    = threadIdx.x;
  const int pl   = t & 63;
  const int c0   = t >> 6;
  const float* src = x + (size_t)b*NCHW + rem0;
  #pragma unroll
  for (int it = 0; it < 16; ++it) {
    int c = c0 + it*4;
    T[c][pl] = src[(size_t)(cg + c)*NHW + pl];
  }
  __syncthreads();
  const int pr = t >> 5;
  const int cp = t & 31;
  #pragma unroll
  for (int it = 0; it < 8; ++it) {
    int pxl = pr + it*8;
    int rem = rem0 + pxl;
    int ho = rem / NW, wo = rem % NW;
    unsigned int pk = ((unsigned int)f2b(T[cp*2+1][pxl]) << 16) | (unsigned int)f2b(T[cp*2][pxl]);
    *(unsigned int*)(xbp + ((size_t)(b*NHP + ho + 1)*NHP + (wo + 1))*256 + cg + cp*2) = pk;
  }
}

// ---------------------------------------------------------------------------
// P2: w [co][ci][3][3] fp32 -> wp [co][k*256+ci] bf16
// ---------------------------------------------------------------------------
__global__ __launch_bounds__(256) void prep_w(
    const float* __restrict__ w, unsigned short* __restrict__ wp)
{
  int i = blockIdx.x*256 + threadIdx.x;    // 589824 exact
  int co = i / 2304;
  int r  = i % 2304;
  int k  = r >> 8;
  int ci = r & 255;
  wp[i] = f2b(w[((size_t)co*256 + ci)*9 + k]);
}

// P3: off_w [18][256][3][3] -> w3p [32 rows][k*256+ci] bf16, rows 18..31 = 0
__global__ __launch_bounds__(256) void prep_w3(
    const float* __restrict__ ow, unsigned short* __restrict__ w3p)
{
  int i = blockIdx.x*256 + threadIdx.x;    // 73728 exact
  int co = i / 2304;
  int r  = i % 2304;
  int k  = r >> 8;
  int ci = r & 255;
  w3p[i] = (co < 18) ? f2b(ow[((size_t)co*256 + ci)*9 + k]) : (unsigned short)0;
}

// ---------------------------------------------------------------------------
// GEMM1: conv3x3 + BN + ReLU -> t1b padded NHWC bf16
// BM=64 BN=256 BK=64, 512 thr = 8 waves (2M x 4N), wave tile 32x64; grid 392
// Software-pipelined: prefetch r+1 regs before soft barrier (loads fly across)
// ---------------------------------------------------------------------------
__global__ __launch_bounds__(512, 4) void gemm_conv1(
    const unsigned short* __restrict__ xbp, const unsigned short* __restrict__ w1p,
    const float* __restrict__ gam, const float* __restrict__ bet,
    const float* __restrict__ mu,  const float* __restrict__ var,
    unsigned short* __restrict__ t1b)
{
  __shared__ unsigned short SMEM[20480];     // Al 4096 | Bl 16384
  unsigned short* Al = SMEM;
  unsigned short* Bl = SMEM + 4096;

  const int m0   = blockIdx.x * 64;
  const int t    = threadIdx.x;
  const int lane = t & 63;
  const int wv   = t >> 6;
  const int wvM  = wv & 1;
  const int wvN  = wv >> 1;
  const int quad = lane >> 4;
  const int l15  = lane & 15;

  const int srow = t >> 3;     // 0..63
  const int seg  = t & 7;
  const int sxor = srow & 7;
  const int px  = m0 + srow;
  const int b   = px / NHW, rem = px % NHW;
  const int ho  = rem / NW, wo = rem % NW;
  const unsigned int pbase = ((unsigned int)(b*NHP + ho)*NHP + wo)*256u + seg*8u;

  f32x4 acc[2][4];
  #pragma unroll
  for (int i = 0; i < 2; ++i)
    #pragma unroll
    for (int j = 0; j < 4; ++j) acc[i][j] = (f32x4)(0.f);

  uint4 pA, pB0, pB1, pB2, pB3;
  {   // prefetch r=0 (k=0 -> ky=kx=0, cic=0)
    pA  = *(const uint4*)(xbp + pbase);
    const unsigned int rb = seg*8u;
    pB0 = *(const uint4*)(w1p + (size_t)(srow      )*2304 + rb);
    pB1 = *(const uint4*)(w1p + (size_t)(srow +  64)*2304 + rb);
    pB2 = *(const uint4*)(w1p + (size_t)(srow + 128)*2304 + rb);
    pB3 = *(const uint4*)(w1p + (size_t)(srow + 192)*2304 + rb);
  }

  for (int r = 0; r < 36; ++r) {
    __syncthreads();                                      // barrier1 (drains prefetch)
    *(uint4*)(&Al[srow*64 + ((seg ^ sxor)*8)]) = pA;
    *(uint4*)(&Bl[(srow      )*64 + ((seg ^ sxor)*8)]) = pB0;
    *(uint4*)(&Bl[(srow +  64)*64 + ((seg ^ sxor)*8)]) = pB1;
    *(uint4*)(&Bl[(srow + 128)*64 + ((seg ^ sxor)*8)]) = pB2;
    *(uint4*)(&Bl[(srow + 192)*64 + ((seg ^ sxor)*8)]) = pB3;
    {   // prefetch r+1 (clamped; redundant reload on last iter)
      const int rn = (r < 35) ? r + 1 : 35;
      const int kn = rn >> 2, cicn = rn & 3;
      const int kyn = kn/3, kxn = kn - kyn*3;
      pA  = *(const uint4*)(xbp + pbase + (unsigned int)((kyn*NHP + kxn)*256 + cicn*64));
      const unsigned int rb = (unsigned int)(rn*64) + seg*8u;
      pB0 = *(const uint4*)(w1p + (size_t)(srow      )*2304 + rb);
      pB1 = *(const uint4*)(w1p + (size_t)(srow +  64)*2304 + rb);
      pB2 = *(const uint4*)(w1p + (size_t)(srow + 128)*2304 + rb);
      pB3 = *(const uint4*)(w1p + (size_t)(srow + 192)*2304 + rb);
    }
    soft_barrier();                                       // barrier2: no vmcnt drain
    #pragma unroll
    for (int kk = 0; kk < 2; ++kk) {
      const int s8 = (kk*4 + quad) ^ (l15 & 7);
      bf16x8 af[2], bfr[4];
      #pragma unroll
      for (int mt = 0; mt < 2; ++mt)
        af[mt] = *(const bf16x8*)(&Al[(wvM*32 + mt*16 + l15)*64 + s8*8]);
      #pragma unroll
      for (int nt = 0; nt < 4; ++nt)
        bfr[nt] = *(const bf16x8*)(&Bl[(wvN*64 + nt*16 + l15)*64 + s8*8]);
      #pragma unroll
      for (int mt = 0; mt < 2; ++mt)
        #pragma unroll
        for (int nt = 0; nt < 4; ++nt)
          acc[mt][nt] = __builtin_amdgcn_mfma_f32_16x16x32_bf16(af[mt], bfr[nt], acc[mt][nt], 0, 0, 0);
    }
  }

  // epilogue: BN+ReLU -> per-wave bounce (32px x 72 shorts) -> padded t1b
  __syncthreads();
  unsigned short* Sw = SMEM + wv*2304;
  #pragma unroll
  for (int nt = 0; nt < 4; ++nt) {
    const int co = wvN*64 + nt*16 + l15;
    const float inv  = gam[co] * rsqrtf(var[co] + EPSV);
    const float beta = bet[co] - mu[co]*inv;
    #pragma unroll
    for (int mt = 0; mt < 2; ++mt) {
      #pragma unroll
      for (int rr = 0; rr < 4; ++rr) {
        const int pxl = mt*16 + quad*4 + rr;
        float val = acc[mt][nt][rr]*inv + beta;
        val = val > 0.f ? val : 0.f;
        Sw[pxl*72 + nt*16 + l15] = f2b(val);
      }
    }
  }
  #pragma unroll
  for (int i = 0; i < 4; ++i) {
    const int pxl = (lane >> 3) + 8*i;
    const int sc  = lane & 7;
    uint4 q = *(const uint4*)(&Sw[pxl*72 + sc*8]);
    const int pg = m0 + wvM*32 + pxl;
    const int bb = pg / NHW, rm = pg % NHW;
    const int hh = rm / NW, ww = rm % NW;
    *(uint4*)(t1b + ((size_t)(bb*NHP + hh + 1)*NHP + ww + 1)*256 + wvN*64 + sc*8) = q;
  }
}

// ---------------------------------------------------------------------------
// GEMM-OFF: offset conv, split-K x4 (9 rounds each), atomicAdd into toff
// BM=64 BN=32, 256 thr = 4 waves (wave 16x32); grid (392,4) -> 24 waves/CU
// ---------------------------------------------------------------------------
__global__ __launch_bounds__(256, 8) void gemm_off(
    const unsigned short* __restrict__ t1b, const unsigned short* __restrict__ w3p,
    const float* __restrict__ ob, float* __restrict__ toff)
{
  __shared__ unsigned short Al[4096];   // 64x64
  __shared__ unsigned short Bl[2048];   // 32x64

  const int m0 = blockIdx.x * 64;
  const int kc = blockIdx.y;            // K chunk 0..3
  const int t    = threadIdx.x;
  const int lane = t & 63;
  const int wv   = t >> 6;
  const int quad = lane >> 4;
  const int l15  = lane & 15;

  const int arow = t >> 2;      // 0..63
  const int as4  = t & 3;
  const int axor = arow & 7;
  const int pxa  = m0 + arow;
  const int ba   = pxa / NHW, rema = pxa % NHW;
  const unsigned int pbase = ((unsigned int)(ba*NHP + rema/NW)*NHP + rema%NW)*256u;

  const int brow = t >> 3;      // 0..31
  const int bs   = t & 7;

  f32x4 acc[2];
  #pragma unroll
  for (int nt = 0; nt < 2; ++nt) {
    float init = 0.f;
    if (kc == 0) { int co = nt*16 + l15; init = (co < 18) ? ob[co] : 0.f; }
    acc[nt] = (f32x4)(init);
  }

  uint4 pA0, pA1, pB;
  {   // prefetch first round r = kc*9
    const int r = kc*9, k = r >> 2, cic = r & 3;
    const int ky = k/3, kx = k - ky*3;
    const unsigned int base = pbase + (unsigned int)((ky*NHP + kx)*256 + cic*64);
    pA0 = *(const uint4*)(t1b + base + as4*8);
    pA1 = *(const uint4*)(t1b + base + (as4+4)*8);
    pB  = *(const uint4*)(w3p + (size_t)brow*2304 + r*64 + bs*8);
  }

  for (int rr = 0; rr < 9; ++rr) {
    const int r = kc*9 + rr;
    __syncthreads();
    *(uint4*)(&Al[arow*64 + ((as4     ^ axor)*8)]) = pA0;
    *(uint4*)(&Al[arow*64 + (((as4+4) ^ axor)*8)]) = pA1;
    *(uint4*)(&Bl[brow*64 + ((bs ^ (brow & 7))*8)]) = pB;
    {
      const int rn = (rr < 8) ? r + 1 : r;
      const int kn = rn >> 2, cicn = rn & 3;
      const int kyn = kn/3, kxn = kn - kyn*3;
      const unsigned int base = pbase + (unsigned int)((kyn*NHP + kxn)*256 + cicn*64);
      pA0 = *(const uint4*)(t1b + base + as4*8);
      pA1 = *(const uint4*)(t1b + base + (as4+4)*8);
      pB  = *(const uint4*)(w3p + (size_t)brow*2304 + rn*64 + bs*8);
    }
    soft_barrier();
    #pragma unroll
    for (int kk = 0; kk < 2; ++kk) {
      const int s8 = (kk*4 + quad) ^ (l15 & 7);
      bf16x8 af = *(const bf16x8*)(&Al[(wv*16 + l15)*64 + s8*8]);
      #pragma unroll
      for (int nt = 0; nt < 2; ++nt) {
        bf16x8 bfr = *(const bf16x8*)(&Bl[(nt*16 + l15)*64 + s8*8]);
        acc[nt] = __builtin_amdgcn_mfma_f32_16x16x32_bf16(af, bfr, acc[nt], 0, 0, 0);
      }
    }
  }
  #pragma unroll
  for (int nt = 0; nt < 2; ++nt) {
    const int co = nt*16 + l15;
    if (co < 18) {
      #pragma unroll
      for (int rr2 = 0; rr2 < 4; ++rr2) {
        const int pg = m0 + wv*16 + quad*4 + rr2;
        const int bb = pg / NHW, rm = pg % NHW;
        atomicAdd(&toff[(size_t)bb*(18*NHW) + (size_t)co*NHW + rm], acc[nt][rr2]);
      }
    }
  }
}

// ---------------------------------------------------------------------------
// GEMM2: deform_conv + BN + residual + ReLU -> out NCHW fp32
// BM=64 BN=256 BK=64, 512 thr; pipelined corner/B prefetch + soft barrier
// ---------------------------------------------------------------------------
__global__ __launch_bounds__(512, 4) void gemm_deform(
    const unsigned short* __restrict__ t1b, const unsigned short* __restrict__ w2p,
    const float* __restrict__ toff, const float* __restrict__ xres,
    const float* __restrict__ gam, const float* __restrict__ bet,
    const float* __restrict__ mu,  const float* __restrict__ var,
    float* __restrict__ outp)
{
  __shared__ unsigned short SMEM[20480];     // Al 4096 | Bl 16384
  unsigned short* Al = SMEM;
  unsigned short* Bl = SMEM + 4096;

  const int m0   = blockIdx.x * 64;
  const int t    = threadIdx.x;
  const int lane = t & 63;
  const int wv   = t >> 6;
  const int wvM  = wv & 1;
  const int wvN  = wv >> 1;
  const int quad = lane >> 4;
  const int l15  = lane & 15;

  const int srow = t >> 3;     // 0..63
  const int seg  = t & 7;
  const int sxor = srow & 7;
  const int px   = m0 + srow;
  const int b    = px / NHW, rem = px % NHW;
  const int ho   = rem / NW, wo = rem % NW;
  const int obb  = b*(18*NHW) + rem;
  const unsigned int prowb = (unsigned int)(b*NHP);

  f32x4 acc[2][4];
  #pragma unroll
  for (int i = 0; i < 2; ++i)
    #pragma unroll
    for (int j = 0; j < 4; ++j) acc[i][j] = (f32x4)(0.f);

  // bilinear coord state for current k
  unsigned int o00, o01, o10, o11;
  float w00, w01, w10, w11;
#define COORDS(KK) {                                                   \
    const int ky_ = (KK)/3, kx_ = (KK) - ky_*3;                        \
    const float offy = toff[obb + (KK)*NHW];                           \
    const float offx = toff[obb + (9+(KK))*NHW];                       \
    const float yf = (float)(ho - 1 + ky_) + offy;                     \
    const float xf = (float)(wo - 1 + kx_) + offx;                     \
    const float y0f = floorf(yf), x0f = floorf(xf);                    \
    const float ty = yf - y0f,   tx = xf - x0f;                        \
    const int y0p = (int)y0f + 1, x0p = (int)x0f + 1;                  \
    const int cy0 = min(max(y0p,   0), NHP-1);                         \
    const int cy1 = min(max(y0p+1, 0), NHP-1);                         \
    const int cx0 = min(max(x0p,   0), NHP-1);                         \
    const int cx1 = min(max(x0p+1, 0), NHP-1);                         \
    w00 = (1.f-ty)*(1.f-tx);  w01 = (1.f-ty)*tx;                       \
    w10 = ty*(1.f-tx);        w11 = ty*tx;                             \
    o00 = ((prowb + cy0)*NHP + cx0)*256u + seg*8u;                     \
    o01 = ((prowb + cy0)*NHP + cx1)*256u + seg*8u;                     \
    o10 = ((prowb + cy1)*NHP + cx0)*256u + seg*8u;                     \
    o11 = ((prowb + cy1)*NHP + cx1)*256u + seg*8u;                     \
  }

  COORDS(0);
  uint4 pc00, pc01, pc10, pc11, pB0, pB1, pB2, pB3;
  {   // prefetch r=0 (cic=0)
    pc00 = *(const uint4*)(t1b + o00);
    pc01 = *(const uint4*)(t1b + o01);
    pc10 = *(const uint4*)(t1b + o10);
    pc11 = *(const uint4*)(t1b + o11);
    const unsigned int rb = seg*8u;
    pB0 = *(const uint4*)(w2p + (size_t)(srow      )*2304 + rb);
    pB1 = *(const uint4*)(w2p + (size_t)(srow +  64)*2304 + rb);
    pB2 = *(const uint4*)(w2p + (size_t)(srow + 128)*2304 + rb);
    pB3 = *(const uint4*)(w2p + (size_t)(srow + 192)*2304 + rb);
  }

  for (int r = 0; r < 36; ++r) {
    __syncthreads();                                   // barrier1
    {   // bilinear + pack from prefetched corners -> Al
      uint4 res;
      {
        float a0 = w00*blo(pc00.x) + w01*blo(pc01.x) + w10*blo(pc10.x) + w11*blo(pc11.x);
        float a1 = w00*bhi(pc00.x) + w01*bhi(pc01.x) + w10*bhi(pc10.x) + w11*bhi(pc11.x);
        res.x = pack_trunc(a0, a1);
      }
      {
        float a0 = w00*blo(pc00.y) + w01*blo(pc01.y) + w10*blo(pc10.y) + w11*blo(pc11.y);
        float a1 = w00*bhi(pc00.y) + w01*bhi(pc01.y) + w10*bhi(pc10.y) + w11*bhi(pc11.y);
        res.y = pack_trunc(a0, a1);
      }
      {
        float a0 = w00*blo(pc00.z) + w01*blo(pc01.z) + w10*blo(pc10.z) + w11*blo(pc11.z);
        float a1 = w00*bhi(pc00.z) + w01*bhi(pc01.z) + w10*bhi(pc10.z) + w11*bhi(pc11.z);
        res.z = pack_trunc(a0, a1);
      }
      {
        float a0 = w00*blo(pc00.w) + w01*blo(pc01.w) + w10*blo(pc10.w) + w11*blo(pc11.w);
        float a1 = w00*bhi(pc00.w) + w01*bhi(pc01.w) + w10*bhi(pc10.w) + w11*bhi(pc11.w);
        res.w = pack_trunc(a0, a1);
      }
      *(uint4*)(&Al[srow*64 + ((seg ^ sxor)*8)]) = res;
    }
    *(uint4*)(&Bl[(srow      )*64 + ((seg ^ sxor)*8)]) = pB0;
    *(uint4*)(&Bl[(srow +  64)*64 + ((seg ^ sxor)*8)]) = pB1;
    *(uint4*)(&Bl[(srow + 128)*64 + ((seg ^ sxor)*8)]) = pB2;
    *(uint4*)(&Bl[(srow + 192)*64 + ((seg ^ sxor)*8)]) = pB3;
    {   // coords for next k, then prefetch r+1
      if ((r & 3) == 3 && r < 35) COORDS((r+1) >> 2);
      const int rn = (r < 35) ? r + 1 : 35;
      const unsigned int cio = (unsigned int)((rn & 3)*64);
      pc00 = *(const uint4*)(t1b + o00 + cio);
      pc01 = *(const uint4*)(t1b + o01 + cio);
      pc10 = *(const uint4*)(t1b + o10 + cio);
      pc11 = *(const uint4*)(t1b + o11 + cio);
      const unsigned int rb = (unsigned int)(rn*64) + seg*8u;
      pB0 = *(const uint4*)(w2p + (size_t)(srow      )*2304 + rb);
      pB1 = *(const uint4*)(w2p + (size_t)(srow +  64)*2304 + rb);
      pB2 = *(const uint4*)(w2p + (size_t)(srow + 128)*2304 + rb);
      pB3 = *(const uint4*)(w2p + (size_t)(srow + 192)*2304 + rb);
    }
    soft_barrier();                                    // barrier2: no vmcnt drain
    #pragma unroll
    for (int kk = 0; kk < 2; ++kk) {
      const int s8 = (kk*4 + quad) ^ (l15 & 7);
      bf16x8 af[2], bfr[4];
      #pragma unroll
      for (int mt = 0; mt < 2; ++mt)
        af[mt] = *(const bf16x8*)(&Al[(wvM*32 + mt*16 + l15)*64 + s8*8]);
      #pragma unroll
      for (int nt = 0; nt < 4; ++nt)
        bfr[nt] = *(const bf16x8*)(&Bl[(wvN*64 + nt*16 + l15)*64 + s8*8]);
      #pragma unroll
      for (int mt = 0; mt < 2; ++mt)
        #pragma unroll
        for (int nt = 0; nt < 4; ++nt)
          acc[mt][nt] = __builtin_amdgcn_mfma_f32_16x16x32_bf16(af[mt], bfr[nt], acc[mt][nt], 0, 0, 0);
    }
  }
#undef COORDS

  // epilogue: per-wave f32 bounce (32px x 33), 2 co-halves -> coalesced NCHW
  __syncthreads();
  float* Sl = (float*)SMEM + wv*1056;
  const int pxl_r = lane & 31;
  const int csel  = lane >> 5;
  const int pg    = m0 + wvM*32 + pxl_r;
  const int bo    = pg / NHW, remo = pg % NHW;
  const size_t obase = (size_t)bo*NCHW + remo;
  #pragma unroll
  for (int h = 0; h < 2; ++h) {
    #pragma unroll
    for (int nt2 = 0; nt2 < 2; ++nt2) {
      const int nt = h*2 + nt2;
      #pragma unroll
      for (int mt = 0; mt < 2; ++mt) {
        #pragma unroll
        for (int rr = 0; rr < 4; ++rr) {
          const int pxl = mt*16 + quad*4 + rr;
          Sl[pxl*33 + nt2*16 + l15] = acc[mt][nt][rr];
        }
      }
    }
    #pragma unroll
    for (int j = 0; j < 16; ++j) {
      const int col = csel*16 + j;
      const int co  = wvN*64 + h*32 + col;
      const float inv  = gam[co] * rsqrtf(var[co] + EPSV);
      const float beta = bet[co] - mu[co]*inv;
      const size_t off = obase + (size_t)co*NHW;
      float val = Sl[pxl_r*33 + col];
      float o = val*inv + beta + xres[off];
      outp[off] = o > 0.f ? o : 0.f;
    }
  }
}

extern "C" void kernel_launch(void* const* d_in, const int* in_sizes, int n_in,
                              void* d_out, int out_size, void* d_ws, size_t ws_size,
                              hipStream_t stream) {
  const float* x   = (const float*)d_in[0];
  const float* w1  = (const float*)d_in[1];
  const float* g1  = (const float*)d_in[2];
  const float* b1  = (const float*)d_in[3];
  const float* m1  = (const float*)d_in[4];
  const float* v1  = (const float*)d_in[5];
  const float* ow  = (const float*)d_in[6];
  const float* ob  = (const float*)d_in[7];
  const float* w2  = (const float*)d_in[8];
  const float* g2  = (const float*)d_in[9];
  const float* b2  = (const float*)d_in[10];
  const float* m2  = (const float*)d_in[11];
  const float* v2  = (const float*)d_in[12];
  float* out = (float*)d_out;

  const size_t PADSZ = (size_t)NB*NHP*NHP*256;
  unsigned short* xbp = (unsigned short*)d_ws;
  unsigned short* t1b = xbp + PADSZ;
  float*          tof = (float*)(t1b + PADSZ);
  unsigned short* w1p = (unsigned short*)(tof + (size_t)NB*18*NHW);
  unsigned short* w2p = w1p + (size_t)589824;
  unsigned short* w3p = w2p + (size_t)589824;

  clear_borders<<<228, 256, 0, stream>>>(xbp, t1b);
  dim3 gp(392, 4, 1);
  prep_x<<<gp, 256, 0, stream>>>(x, xbp);
  prep_w<<<2304, 256, 0, stream>>>(w1, w1p);
  prep_w<<<2304, 256, 0, stream>>>(w2, w2p);
  prep_w3<<<288, 256, 0, stream>>>(ow, w3p);
  hipMemsetAsync(tof, 0, (size_t)NB*18*NHW*sizeof(float), stream);

  gemm_conv1<<<392, 512, 0, stream>>>(xbp, w1p, g1, b1, m1, v1, t1b);
  dim3 go(392, 4, 1);
  gemm_off<<<go, 256, 0, stream>>>(t1b, w3p, ob, tof);
  gemm_deform<<<392, 512, 0, stream>>>(t1b, w2p, tof, x, g2, b2, m2, v2, out);
}